// Round 4
// baseline (1138.375 us; speedup 1.0000x reference)
//
#include <hip/hip_runtime.h>
#include <hip/hip_bf16.h>

#define NNODES 50000
#define NEDGES 800000
#define NEG_SLOPE 0.2f
#define N_PAD 50176   // 49*1024
#define EB 6250       // edge blocks = NEDGES/128
#define TILE 192      // max edge rows per block (128 window + maxdeg<64 overhang)

typedef float f32x4 __attribute__((ext_vector_type(4)));
typedef float f32x2 __attribute__((ext_vector_type(2)));
typedef __bf16 bf16x8 __attribute__((ext_vector_type(8)));
typedef __bf16 bf16x4 __attribute__((ext_vector_type(4)));
typedef __bf16 bf16x2 __attribute__((ext_vector_type(2)));

// ---------------- node-projection GEMM: C[M,128] = A[M,128] @ W^T + bias (fp32 out) ----
__global__ __launch_bounds__(256, 2) void gemm_proj(
    const float* __restrict__ A, const float* __restrict__ W,
    const float* __restrict__ bias, float* __restrict__ outp, int M)
{
  __shared__ __bf16 sA[128*128];
  __shared__ __bf16 sB[128*128];
  const int t = threadIdx.x;
  const int m0 = blockIdx.x * 128;

  #pragma unroll
  for (int it = 0; it < 16; ++it){
    int lin = it*1024 + t*4;
    int r = lin >> 7, cx = lin & 127;
    f32x4 v = {0.f, 0.f, 0.f, 0.f};
    int gr = m0 + r;
    if (gr < M) v = *(const f32x4*)(A + (size_t)gr*128 + cx);
    int kb = cx >> 3, ko = cx & 7;
    int off = r*128 + ((kb ^ (r & 15)) << 3) + ko;
    bf16x4 pk = { (__bf16)v.x, (__bf16)v.y, (__bf16)v.z, (__bf16)v.w };
    *(bf16x4*)(sA + off) = pk;
  }
  #pragma unroll
  for (int it = 0; it < 16; ++it){
    int lin = it*1024 + t*4;
    int r = lin >> 7, cx = lin & 127;
    f32x4 v = *(const f32x4*)(W + lin);
    int kb = cx >> 3, ko = cx & 7;
    int off = r*128 + ((kb ^ (r & 15)) << 3) + ko;
    bf16x4 pk = { (__bf16)v.x, (__bf16)v.y, (__bf16)v.z, (__bf16)v.w };
    *(bf16x4*)(sB + off) = pk;
  }
  __syncthreads();

  const int w = t >> 6, lane = t & 63;
  const int rsel = lane & 15, quad = lane >> 4;
  f32x4 acc[2][8];
  f32x4 zero = {0.f, 0.f, 0.f, 0.f};
  #pragma unroll
  for (int mi = 0; mi < 2; ++mi)
    #pragma unroll
    for (int ni = 0; ni < 8; ++ni) acc[mi][ni] = zero;

  #pragma unroll
  for (int kk = 0; kk < 4; ++kk){
    int kb0 = kk*4 + quad;
    bf16x8 af[2], bf[8];
    #pragma unroll
    for (int mi = 0; mi < 2; ++mi){
      int r = w*32 + mi*16 + rsel;
      af[mi] = *(const bf16x8*)(sA + r*128 + ((kb0 ^ (r & 15)) << 3));
    }
    #pragma unroll
    for (int ni = 0; ni < 8; ++ni){
      int r = ni*16 + rsel;
      bf[ni] = *(const bf16x8*)(sB + r*128 + ((kb0 ^ (r & 15)) << 3));
    }
    #pragma unroll
    for (int mi = 0; mi < 2; ++mi)
      #pragma unroll
      for (int ni = 0; ni < 8; ++ni)
        acc[mi][ni] = __builtin_amdgcn_mfma_f32_16x16x32_bf16(af[mi], bf[ni], acc[mi][ni], 0, 0, 0);
  }

  // C/D: col = lane&15 (+16*ni), row = quad*4 + r4 (+16*mi + 32*w)
  #pragma unroll
  for (int mi = 0; mi < 2; ++mi){
    #pragma unroll
    for (int ni = 0; ni < 8; ++ni){
      #pragma unroll
      for (int r4 = 0; r4 < 4; ++r4){
        int grow = m0 + w*32 + mi*16 + quad*4 + r4;
        int col = ni*16 + rsel;
        if (grow < M)
          outp[(size_t)grow*128 + col] = acc[mi][ni][r4] + bias[col];
      }
    }
  }
}

// ---------------- CSR build ----------------
__global__ void hist_kernel(const int* __restrict__ dst, int* __restrict__ deg){
  int e = blockIdx.x*256 + threadIdx.x;
  atomicAdd(&deg[dst[e]], 1);
}

__global__ void scan_local(const int* __restrict__ deg, int* __restrict__ scanned,
                           int* __restrict__ bsum){
  __shared__ int s[1024];
  int t = threadIdx.x, i = blockIdx.x*1024 + t;
  int v = deg[i];
  s[t] = v; __syncthreads();
  #pragma unroll
  for (int off = 1; off < 1024; off <<= 1){
    int x = (t >= off) ? s[t-off] : 0;
    __syncthreads();
    s[t] += x;
    __syncthreads();
  }
  scanned[i] = s[t] - v;          // exclusive
  if (t == 1023) bsum[blockIdx.x] = s[t];
}

__global__ void scan_sums(int* __restrict__ bsum){  // 1 block, 64 threads, 49 valid
  __shared__ int s[64];
  int t = threadIdx.x;
  int v = (t < 49) ? bsum[t] : 0;
  s[t] = v; __syncthreads();
  #pragma unroll
  for (int off = 1; off < 64; off <<= 1){
    int x = (t >= off) ? s[t-off] : 0;
    __syncthreads();
    s[t] += x;
    __syncthreads();
  }
  bsum[t] = s[t] - v;             // exclusive block bases
}

__global__ void scan_add(const int* __restrict__ scanned, const int* __restrict__ bsum,
                         int* __restrict__ row_start, int* __restrict__ cursor){
  int i = blockIdx.x*256 + threadIdx.x;
  if (i < N_PAD){
    int val = scanned[i] + bsum[i >> 10];
    row_start[i] = val;
    cursor[i] = val;
  }
}

// eperm[pos] = edge id at CSR position pos; src_perm[pos] = src of that edge
__global__ void scatter_kernel(const int* __restrict__ dst, const int* __restrict__ src,
                               int* __restrict__ cursor, int* __restrict__ eperm,
                               int* __restrict__ src_perm){
  int e = blockIdx.x*256 + threadIdx.x;
  int pos = atomicAdd(&cursor[dst[e]], 1);
  eperm[pos] = e;
  src_perm[pos] = src[e];
}

// per-block node/edge ranges: node n belongs to block min(row_start[n]>>7, EB-1)
__global__ void node_ranges(const int* __restrict__ row_start, const int* __restrict__ deg,
                            int* __restrict__ nlo, int* __restrict__ pend){
  int n = blockIdx.x*256 + threadIdx.x;
  if (n >= NNODES) return;
  int rs = row_start[n];
  int b = rs >> 7; if (b > EB-1) b = EB-1;
  atomicMin(&nlo[b], n);
  atomicMax(&pend[b], rs + deg[n]);
}

// ---------------- fused: edge projection (MFMA) + score + softmax + aggregation -------
// Block b owns nodes {n : row_start[n]>>7 == b}. It gathers their full edge range
// [pstart, pend) (<= TILE rows, since maxdeg << 64 for Poisson(16) degrees), projects
// efeat rows with W_edge via MFMA into LDS (bf16), then runs the validated per-node
// online-softmax aggregation reading fe straight from LDS. fe never touches HBM.
__global__ __launch_bounds__(256, 2) void fused_edge(
    const float* __restrict__ efeat, const float* __restrict__ W,
    const int* __restrict__ eperm, const int* __restrict__ src_perm,
    const int* __restrict__ row_start, const int* __restrict__ deg,
    const int* __restrict__ nlo_arr, const int* __restrict__ pend_arr,
    const float* __restrict__ fs, const float* __restrict__ fd,
    const float* __restrict__ attn, float* __restrict__ out)
{
  __shared__ __bf16 sA[TILE*128];   // efeat tile, then reused as fe tile
  __shared__ __bf16 sB[128*128];    // W_edge
  const int b = blockIdx.x, t = threadIdx.x;
  const int nlo = nlo_arr[b];
  if (nlo >= NNODES) return;        // empty block (init 0x7F7F7F7F)
  const int pstart = row_start[nlo];
  int cnt_e = pend_arr[b] - pstart;
  if (cnt_e > TILE) cnt_e = TILE;
  const int cnt_r = (cnt_e + 15) & ~15;

  // stage W (same for every block; L2-resident)
  #pragma unroll
  for (int it = 0; it < 16; ++it){
    int lin = it*1024 + t*4;
    int r = lin >> 7, cx = lin & 127;
    f32x4 v = *(const f32x4*)(W + lin);
    int kb = cx >> 3, ko = cx & 7;
    int off = r*128 + ((kb ^ (r & 15)) << 3) + ko;
    bf16x4 pk = { (__bf16)v.x, (__bf16)v.y, (__bf16)v.z, (__bf16)v.w };
    *(bf16x4*)(sB + off) = pk;
  }
  // stage gathered efeat rows: 32 threads per row (32 x f32x4 = 512 B)
  {
    int g = t >> 5, lx = t & 31, cx = lx << 2;
    for (int r = g; r < cnt_r; r += 8){
      f32x4 v = {0.f, 0.f, 0.f, 0.f};
      if (r < cnt_e){
        int eid = eperm[pstart + r];
        v = *(const f32x4*)(efeat + (size_t)eid*128 + cx);
      }
      int kb = cx >> 3, ko = cx & 7;
      int off = r*128 + ((kb ^ (r & 15)) << 3) + ko;
      bf16x4 pk = { (__bf16)v.x, (__bf16)v.y, (__bf16)v.z, (__bf16)v.w };
      *(bf16x4*)(sA + off) = pk;
    }
  }
  __syncthreads();

  const int w = t >> 6, lane = t & 63;
  const int rsel = lane & 15, quad = lane >> 4;
  // wave w computes M-tiles {w, w+4, w+8} -> base rows w*16 + mi*64
  f32x4 acc[3][8];
  f32x4 zero = {0.f, 0.f, 0.f, 0.f};
  #pragma unroll
  for (int mi = 0; mi < 3; ++mi)
    #pragma unroll
    for (int ni = 0; ni < 8; ++ni) acc[mi][ni] = zero;

  #pragma unroll
  for (int kk = 0; kk < 4; ++kk){
    int kb0 = kk*4 + quad;
    bf16x8 af[3], bf[8];
    #pragma unroll
    for (int ni = 0; ni < 8; ++ni){
      int r = ni*16 + rsel;
      bf[ni] = *(const bf16x8*)(sB + r*128 + ((kb0 ^ (r & 15)) << 3));
    }
    #pragma unroll
    for (int mi = 0; mi < 3; ++mi){
      int tb = w*16 + mi*64;
      if (tb < cnt_e){
        int r = tb + rsel;
        af[mi] = *(const bf16x8*)(sA + r*128 + ((kb0 ^ (r & 15)) << 3));
      }
    }
    #pragma unroll
    for (int mi = 0; mi < 3; ++mi){
      int tb = w*16 + mi*64;
      if (tb < cnt_e)
        #pragma unroll
        for (int ni = 0; ni < 8; ++ni)
          acc[mi][ni] = __builtin_amdgcn_mfma_f32_16x16x32_bf16(af[mi], bf[ni], acc[mi][ni], 0, 0, 0);
    }
  }
  __syncthreads();   // everyone done reading sA

  // write fe tile back to sA (bf16, same swizzle). C/D: col=ni*16+rsel, row=tb+quad*4+r4
  #pragma unroll
  for (int mi = 0; mi < 3; ++mi){
    int tb = w*16 + mi*64;
    if (tb < cnt_e){
      #pragma unroll
      for (int ni = 0; ni < 8; ++ni){
        int col = ni*16 + rsel;
        int kb = col >> 3, ko = col & 7;
        #pragma unroll
        for (int r4 = 0; r4 < 4; ++r4){
          int row = tb + quad*4 + r4;
          sA[row*128 + ((kb ^ (row & 15)) << 3) + ko] = (__bf16)acc[mi][ni][r4];
        }
      }
    }
  }
  __syncthreads();

  // ---- per-node online-softmax aggregation (validated math from R3) ----
  const int c = lane << 1;
  const int ckb = c >> 3, cko = c & 7;
  f32x2 atv = *(const f32x2*)(attn + c);
  for (int n = nlo + w; n < NNODES; n += 4){
    int rs = row_start[n];
    int bb = rs >> 7; if (bb > EB-1) bb = EB-1;
    if (bb != b) break;
    int dg = deg[n];
    f32x2 fdv = *(const f32x2*)(fd + (size_t)n*128 + c);
    float acc0 = 0.f, acc1 = 0.f, zs = 0.f;
    int row0 = rs - pstart;
    for (int base = 0; base < dg; base += 64){
      int cnt = min(64, dg - base);
      int si = 0;
      if (lane < cnt) si = src_perm[rs + base + lane];
      for (int j = 0; j < cnt; ++j){
        int s = __shfl(si, j, 64);
        f32x2 fsv = *(const f32x2*)(fs + (size_t)s*128 + c);
        int p = row0 + base + j;
        bf16x2 fev = *(const bf16x2*)(sA + p*128 + ((ckb ^ (p & 15)) << 3) + cko);
        float v0 = fsv.x + (float)fev.x;
        float v1 = fsv.y + (float)fev.y;
        float t0 = v0 + fdv.x; t0 = t0 >= 0.f ? t0 : NEG_SLOPE*t0;
        float t1 = v1 + fdv.y; t1 = t1 >= 0.f ? t1 : NEG_SLOPE*t1;
        float p8 = t0*atv.x + t1*atv.y;
        p8 += __shfl_xor(p8, 1);
        p8 += __shfl_xor(p8, 2);
        p8 += __shfl_xor(p8, 4);       // per-head score (8 lanes/head, head = lane>>3)
        float ex = __expf(p8);
        acc0 += ex*v0; acc1 += ex*v1; zs += ex;
      }
    }
    float rz = zs > 0.f ? 1.f/zs : 0.f;
    float o0 = acc0*rz, o1 = acc1*rz;
    f32x2 ov = { o0 > 0.f ? o0 : 0.f, o1 > 0.f ? o1 : 0.f };
    *(f32x2*)(out + (size_t)n*128 + c) = ov;
  }
}

extern "C" void kernel_launch(void* const* d_in, const int* in_sizes, int n_in,
                              void* d_out, int out_size, void* d_ws, size_t ws_size,
                              hipStream_t stream)
{
  const float* x      = (const float*)d_in[0];
  const float* efeat  = (const float*)d_in[1];
  const int*   src    = (const int*)d_in[2];
  const int*   dst    = (const int*)d_in[3];
  const float* W_src  = (const float*)d_in[4];
  const float* b_src  = (const float*)d_in[5];
  const float* W_dst  = (const float*)d_in[6];
  const float* b_dst  = (const float*)d_in[7];
  const float* W_edge = (const float*)d_in[8];
  const float* attn   = (const float*)d_in[9];

  char* ws = (char*)d_ws;
  float* feat_src  = (float*)(ws + 0);            // 25,600,000
  float* feat_dst  = (float*)(ws + 25600000);     // 25,600,000
  int*   eperm     = (int*)  (ws + 51200000);     //  3,200,000
  int*   src_perm  = (int*)  (ws + 54400000);     //  3,200,000
  int*   row_start = (int*)  (ws + 57600000);     //    200,704
  int*   cursor    = (int*)  (ws + 57800704);     //    200,704
  int*   scanned   = (int*)  (ws + 58001408);     //    200,704
  int*   deg       = (int*)  (ws + 58202112);     //    200,704  } zeroed
  int*   pend      = (int*)  (ws + 58402816);     //     25,000  } zeroed
  int*   bsum      = (int*)  (ws + 58427816);     //      1,024
  int*   nlo       = (int*)  (ws + 58428840);     //     25,000  (0x7F init)

  hipMemsetAsync(deg, 0, 225704, stream);         // deg + pend
  hipMemsetAsync(nlo, 0x7F, 25000, stream);       // nlo = 0x7F7F7F7F > NNODES

  // CSR build
  hist_kernel   <<<3125, 256, 0, stream>>>(dst, deg);
  scan_local    <<<49, 1024, 0, stream>>>(deg, scanned, bsum);
  scan_sums     <<<1, 64, 0, stream>>>(bsum);
  scan_add      <<<196, 256, 0, stream>>>(scanned, bsum, row_start, cursor);
  scatter_kernel<<<3125, 256, 0, stream>>>(dst, src, cursor, eperm, src_perm);
  node_ranges   <<<196, 256, 0, stream>>>(row_start, deg, nlo, pend);

  // node projections
  gemm_proj<<<391, 256, 0, stream>>>(x, W_src, b_src, feat_src, NNODES);
  gemm_proj<<<391, 256, 0, stream>>>(x, W_dst, b_dst, feat_dst, NNODES);

  // fused edge projection + score + edge-softmax + aggregation
  fused_edge<<<EB, 256, 0, stream>>>(efeat, W_edge, eperm, src_perm, row_start, deg,
                                     nlo, pend, feat_src, feat_dst, attn, (float*)d_out);
}